// Round 10
// baseline (515.433 us; speedup 1.0000x reference)
//
#include <hip/hip_runtime.h>
#include <hip/hip_bf16.h>
#include <math.h>

typedef short bf16x8 __attribute__((ext_vector_type(8)));
typedef _Float16 half8 __attribute__((ext_vector_type(8)));
typedef float f32x4 __attribute__((ext_vector_type(4)));

#define B_   128
#define T_   800
#define E_   100
#define HC   192       // 2H
#define OUTV 102400    // B*C*O

__device__ inline float squash_scale(float n2) {
    return (n2 / (n2 + 1.f)) * rsqrtf(fmaxf(n2, 1e-30f));
}

__device__ inline unsigned short bf16_bits(float x) {
    __hip_bfloat16 h = __float2bfloat16(x);
    return *(unsigned short*)&h;
}

__device__ inline unsigned int pack_bf16x2(float a, float b) {
    return (unsigned int)bf16_bits(a) | ((unsigned int)bf16_bits(b) << 16);
}

__device__ inline void split_hilo(float x, unsigned short& hi, unsigned short& lo) {
    __hip_bfloat16 h = __float2bfloat16(x);
    float hf = __bfloat162float(h);
    hi = *(unsigned short*)&h;
    __hip_bfloat16 l = __float2bfloat16(x - hf);
    lo = *(unsigned short*)&l;
}

__device__ inline float f16u_to_f(unsigned short s) {
    _Float16 h;
    __builtin_memcpy(&h, &s, 2);
    return (float)h;
}

__device__ inline unsigned short f16_bits(float x) {
    _Float16 h = (_Float16)x;
    unsigned short b;
    __builtin_memcpy(&b, &h, 2);
    return b;
}

__device__ inline unsigned int pack_f16x2(float a, float b) {
    return (unsigned int)f16_bits(a) | ((unsigned int)f16_bits(b) << 16);
}

__device__ inline float fast_sigmoid(float x) { return 1.f / (1.f + __expf(-x)); }
__device__ inline float fast_tanh(float x) {
    float e = __expf(2.f * x);
    return 1.f - 2.f / (e + 1.f);
}

// LDS-only barrier: make LDS writes visible and sync the block WITHOUT
// draining vmcnt (global loads/stores stay in flight across the barrier).
__device__ inline void bar_lds_only() {
    asm volatile("s_waitcnt lgkmcnt(0)" ::: "memory");
    __builtin_amdgcn_s_barrier();
    asm volatile("" ::: "memory");
}

// 16-byte async global->LDS copy (per-lane addresses must be wave-linear in
// steps of 16 B on the LDS side — guaranteed by o = tid*8 (+ wave-uniform)).
__device__ inline void stage16(const unsigned short* g, unsigned short* l) {
#if __has_builtin(__builtin_amdgcn_global_load_lds)
    __builtin_amdgcn_global_load_lds(
        (const __attribute__((address_space(1))) unsigned int*)g,
        (__attribute__((address_space(3))) unsigned int*)l, 16, 0, 0);
#else
    *(uint4*)l = *(const uint4*)g;
#endif
}

// ---------------------------------------------------------------------------
// Kernel P (v2): pre-convert wih (both dirs) to the exact f16 tile image
// AND A1 (transposed) to hi/lo bf16 LDS tile images.
//   Bpre[0 .. 87040)          : wih f16 tiles ([u*320+gc][136], q = k)
//   Bpre[87040 .. 99840)      : A1T hi plane  [64][200]  (nn<50, k<192)
//   Bpre[99840 .. 112640)     : A1T lo plane  [64][200]
// ---------------------------------------------------------------------------
__global__ __launch_bounds__(256) void k_prep(
        const float* __restrict__ wih0, const float* __restrict__ wih1,
        const float* __restrict__ A1,
        unsigned short* __restrict__ Bpre)
{
    int idx = blockIdx.x * 256 + threadIdx.x;       // grid 390*256 == 99840
    if (idx >= 99840) return;
    if (idx < 87040) {
        int q = idx % 136;
        int r = idx / 136;                          // u*320 + gc
        int u2 = r / 320, gc = r % 320;
        const float* wih = u2 ? wih1 : wih0;
        unsigned short v = 0;
        if (q < 100 && gc < 288) v = f16_bits(wih[(size_t)gc * E_ + q]);
        Bpre[idx] = v;
    } else {
        int idx2 = idx - 87040;                     // [0, 12800)
        int nn = idx2 / 200, k = idx2 - nn * 200;
        unsigned short vh = 0, vl = 0;
        if (nn < 50 && k < 192) split_hilo(A1[k * 50 + nn], vh, vl);
        Bpre[87040 + idx2] = vh;
        Bpre[99840 + idx2] = vl;
    }
}

// ---------------------------------------------------------------------------
// Kernel A2 (round-10): emb gather -> f16, K padded to 128.
// xx16[m][128] halves, m = i*800 + t.  Same pair-guarded conversion as the
// old gi2b A-staging -> bit-identical MFMA A fragments.
// ---------------------------------------------------------------------------
__global__ __launch_bounds__(256) void k_embg(
        const int* __restrict__ tokens, const float* __restrict__ emb,
        unsigned short* __restrict__ xx16)
{
    const int m0 = blockIdx.x * 64;      // 1600 blocks
    const int tid = threadIdx.x;
    __shared__ int tok[64];
    if (tid < 64) tok[tid] = tokens[m0 + tid];
    __syncthreads();
    for (int e = tid; e < 1024; e += 256) {
        int r = e >> 4, seg = e & 15;
        const float* ap = emb + (size_t)tok[r] * E_ + seg * 8;
        unsigned int w[4];
#pragma unroll
        for (int pq = 0; pq < 4; ++pq) {
            int k0 = seg * 8 + pq * 2;
            float2 f = {0.f, 0.f};
            if (k0 + 1 < E_) f = *(const float2*)(ap + pq * 2);
            w[pq] = pack_f16x2(f.x, f.y);
        }
        *(uint4*)(xx16 + (size_t)(m0 + r) * 128 + seg * 8) = *(uint4*)w;
    }
}

// ---------------------------------------------------------------------------
// Kernel B (v4f, round-10): MFMA GRU with IN-STEP gi computation.
// Grid (200, ndir) x 384.  Structure = round-4-verified gru4 (400 blocks,
// h16 dbuf, LDS-only barrier, reader-rg shuffle routing), with the gi3
// global stream replaced by 12 h-independent MFMAs per step:
//   gi[t][gc] = emb_f16[i,t] @ wih_f16[gc]  (wih frags pinned in 48 VGPRs,
//   same bits + same kk chain order as old k_gi2b -> identical values
//   pre-rounding; the f16 round-trip is gone -> strictly closer to f32 ref).
// A (emb) fragments prefetched 1 step ahead (lanes c16<4, 4 x uint4).
// gi routed to (t=rg, col j) with the same shuffle pattern as the whh term.
// ---------------------------------------------------------------------------
__global__ __launch_bounds__(384, 2) void k_gru4f(
        const unsigned short* __restrict__ xx16,
        const unsigned short* __restrict__ Bpre,
        const float* __restrict__ bih0, const float* __restrict__ bih1,
        const float* __restrict__ whh_f, const float* __restrict__ whh_b,
        const float* __restrict__ bhh_f, const float* __restrict__ bhh_b,
        __hip_bfloat16* __restrict__ hout, int uoff)
{
    const int tc = blockIdx.x;           // 0..199 (4 t-rows each)
    const int u  = blockIdx.y + uoff;    // 0 fwd, 1 bwd
    const int tid = threadIdx.x;
    const int wv2 = tid >> 6;            // col chunk cc = 0..5
    const int l   = tid & 63;
    const int c16 = l & 15, rg = l >> 4; // rg = local t-row (0..3) / k-octet
    const float* whh = u ? whh_b : whh_f;
    const float* bhh = u ? bhh_b : bhh_f;
    const float* bih = u ? bih1 : bih0;

    __shared__ _Float16 h16[2][16 * 104];   // rows 4..15 stay zero (M pad)

    // ---- whh fragments: 3 gates x 3 kchunks for col j = wv2*16 + c16 ----
    const int j = wv2 * 16 + c16;
    half8 bw[3][3];
    float bias[3];
#pragma unroll
    for (int g = 0; g < 3; ++g) {
        int n = g * 96 + j;
        bias[g] = bhh[n];
#pragma unroll
        for (int kc = 0; kc < 3; ++kc) {
            const float* wp = whh + (size_t)n * 96 + kc * 32 + rg * 8;
            float4 f0 = *(const float4*)wp;
            float4 f1 = *(const float4*)(wp + 4);
            half8 hb;
            hb[0] = (_Float16)f0.x; hb[1] = (_Float16)f0.y;
            hb[2] = (_Float16)f0.z; hb[3] = (_Float16)f0.w;
            hb[4] = (_Float16)f1.x; hb[5] = (_Float16)f1.y;
            hb[6] = (_Float16)f1.z; hb[7] = (_Float16)f1.w;
            bw[g][kc] = hb;
        }
    }
    // ---- wih fragments (f16 image) + bih bias at this lane's col j ----
    half8 wB[3][4];
    float bihl[3];
#pragma unroll
    for (int g = 0; g < 3; ++g) {
        int gc = g * 96 + j;
        bihl[g] = bih[gc];
#pragma unroll
        for (int kk = 0; kk < 4; ++kk)
            wB[g][kk] = *(const half8*)(Bpre + (size_t)(u * 320 + gc) * 136 + kk * 32 + rg * 8);
    }
#pragma unroll
    for (int g = 0; g < 3; ++g) {
#pragma unroll
        for (int kc = 0; kc < 3; ++kc) asm volatile("" : "+v"(bw[g][kc]));
#pragma unroll
        for (int kk = 0; kk < 4; ++kk) asm volatile("" : "+v"(wB[g][kk]));
        asm volatile("" : "+v"(bias[g]));
        asm volatile("" : "+v"(bihl[g]));
    }

    for (int idx = tid; idx < 2 * 16 * 104; idx += 384)
        (&h16[0][0])[idx] = (_Float16)0.f;
    float hst = 0.f;
    __syncthreads();

    // ---- A (emb) addressing: lane reads row tA = tc*4 + c16 (c16<4) ----
    const int i0 = u ? 127 : 0;
    const uint4* xbase = (const uint4*)xx16;
    long long pA = ((long long)i0 * 800 + tc * 4 + (c16 & 3)) * 16;  // uint4 units
    const long long dA = (u ? -1LL : 1LL) * 12800;                   // 800*16

    uint4 curA[4] = {};
    uint4 nxA[4]  = {};
    if (c16 < 4) {
#pragma unroll
        for (int kk = 0; kk < 4; ++kk) curA[kk] = xbase[pA + kk * 4 + rg];
    }

    // ---- hout running pointer ----
    const int t = tc * 4 + rg;
    __hip_bfloat16* hptr = hout + ((size_t)i0 * T_ + t) * HC + u * 96 + j;
    const long long hstep = (u ? -1LL : 1LL) * (T_ * HC);

    int cb = 0;

    for (int s = 0; s < 128; ++s) {
        // issue next step's A loads FIRST (full step of latency cover; the
        // LDS-only barrier never drains vmcnt)
        if (s < 127 && c16 < 4) {
            pA += dA;
#pragma unroll
            for (int kk = 0; kk < 4; ++kk) nxA[kk] = xbase[pA + kk * 4 + rg];
        }

        // gi MFMAs: independent of h16 -> fill the ds_read latency
        f32x4 gac[3];
#pragma unroll
        for (int g = 0; g < 3; ++g) {
            f32x4 c = {0.f, 0.f, 0.f, 0.f};
#pragma unroll
            for (int kk = 0; kk < 4; ++kk) {
                union { uint4 u4; half8 h8; } cv; cv.u4 = curA[kk];
                c = __builtin_amdgcn_mfma_f32_16x16x32_f16(cv.h8, wB[g][kk], c, 0, 0, 0);
            }
            gac[g] = c;
        }

        const _Float16* hb = &h16[cb][0];
        half8 a0 = *(const half8*)(&hb[c16 * 104 + 0  + rg * 8]);
        half8 a1 = *(const half8*)(&hb[c16 * 104 + 32 + rg * 8]);
        half8 a2 = *(const half8*)(&hb[c16 * 104 + 64 + rg * 8]);

        f32x4 acc[3];
#pragma unroll
        for (int g = 0; g < 3; ++g) {
            f32x4 c = {0.f, 0.f, 0.f, 0.f};
            c = __builtin_amdgcn_mfma_f32_16x16x32_f16(a0, bw[g][0], c, 0, 0, 0);
            c = __builtin_amdgcn_mfma_f32_16x16x32_f16(a1, bw[g][1], c, 0, 0, 0);
            c = __builtin_amdgcn_mfma_f32_16x16x32_f16(a2, bw[g][2], c, 0, 0, 0);
            acc[g] = c;
        }

        // route C[rg][c16] -> this lane for BOTH terms: pull all 4 regs from
        // lane c16 (quad 0), select by the READER's rg. (wave-local)
        float rt[3], gt[3];
#pragma unroll
        for (int g = 0; g < 3; ++g) {
            float v0 = __shfl(acc[g][0], c16);
            float v1 = __shfl(acc[g][1], c16);
            float v2 = __shfl(acc[g][2], c16);
            float v3 = __shfl(acc[g][3], c16);
            float lo = (rg & 1) ? v1 : v0;
            float hi = (rg & 1) ? v3 : v2;
            rt[g] = (rg & 2) ? hi : lo;
            float w0 = __shfl(gac[g][0], c16);
            float w1 = __shfl(gac[g][1], c16);
            float w2 = __shfl(gac[g][2], c16);
            float w3 = __shfl(gac[g][3], c16);
            float glo = (rg & 1) ? w1 : w0;
            float ghi = (rg & 1) ? w3 : w2;
            gt[g] = (rg & 2) ? ghi : glo;
        }

        float r  = fast_sigmoid(gt[0] + bihl[0] + rt[0] + bias[0]);
        float z  = fast_sigmoid(gt[1] + bihl[1] + rt[1] + bias[1]);
        float nn = fast_tanh(gt[2] + bihl[2] + r * (rt[2] + bias[2]));
        float hp = (1.f - z) * nn + z * hst;
        hst = hp;

        h16[cb ^ 1][rg * 104 + j] = (_Float16)hp;   // write OTHER buffer
        *hptr = __float2bfloat16(hp);

        bar_lds_only();                  // lgkmcnt(0) + s_barrier, no vmcnt

#pragma unroll
        for (int kk = 0; kk < 4; ++kk) curA[kk] = nxA[kk];
        hptr += hstep;
        cb ^= 1;
    }
}

// ---------------------------------------------------------------------------
// Kernel C (fused att1+att2): att = softmax(tanh(h@A1+b1)@A2 + b2, axis=-1).
// ---------------------------------------------------------------------------
__global__ __launch_bounds__(256) void k_attf(
        const __hip_bfloat16* __restrict__ h,
        const unsigned short* __restrict__ Bpre,   // A1 tiles at +87040
        const float* __restrict__ b1,
        const float* __restrict__ A2,
        const float* __restrict__ b2,
        float* __restrict__ att)
{
    const int m0 = blockIdx.x * 64;      // 1600 blocks
    const int tid = threadIdx.x;
    __shared__ __align__(16) unsigned char poolA[64 * 200 * 2];  // At | phase2
    __shared__ __align__(16) unsigned short Bhi[64 * 200];
    __shared__ __align__(16) unsigned short Blo[64 * 200];
    unsigned short* At = (unsigned short*)poolA;
    float* ttl = (float*)poolA;                   // [64][52]  13312 B
    float* A2l = (float*)(poolA + 13312);         // 600 f32    2400 B
    float* b2l = (float*)(poolA + 15712);         // 12 f32       48 B
    float* scl = (float*)(poolA + 15760);         // [64][12]   3072 B

    for (int idx = tid; idx < 64 * 96; idx += 256) {
        int r = idx / 96, p = idx - r * 96;
        unsigned int v = *(const unsigned int*)((const unsigned short*)h + ((size_t)(m0 + r) * HC + 2 * p));
        *(unsigned int*)(&At[r * 200 + 2 * p]) = v;
    }
    {
        const unsigned short* hsrc = Bpre + 87040;
        const unsigned short* lsrc = Bpre + 99840;
        for (int o = tid * 8; o < 12800; o += 2048) {
            stage16(hsrc + o, &Bhi[0] + o);
            stage16(lsrc + o, &Blo[0] + o);
        }
    }
    __syncthreads();
    const int w = tid >> 6, l = tid & 63;
    const int lr = l & 15, quad = l >> 4;
    f32x4 z4 = {0.f, 0.f, 0.f, 0.f};
    f32x4 acc[4];
#pragma unroll
    for (int i = 0; i < 4; ++i) acc[i] = z4;
#pragma unroll
    for (int kk = 0; kk < 6; ++kk) {
        bf16x8 af = *(const bf16x8*)(&At[(w * 16 + lr) * 200 + kk * 32 + quad * 8]);
#pragma unroll
        for (int ns = 0; ns < 4; ++ns) {
            bf16x8 bh = *(const bf16x8*)(&Bhi[(ns * 16 + lr) * 200 + kk * 32 + quad * 8]);
            bf16x8 bl = *(const bf16x8*)(&Blo[(ns * 16 + lr) * 200 + kk * 32 + quad * 8]);
            acc[ns] = __builtin_amdgcn_mfma_f32_16x16x32_bf16(af, bh, acc[ns], 0, 0, 0);
            acc[ns] = __builtin_amdgcn_mfma_f32_16x16x32_bf16(af, bl, acc[ns], 0, 0, 0);
        }
    }
    __syncthreads();                     // At dead -> ttl overlay safe
#pragma unroll
    for (int ns = 0; ns < 4; ++ns) {
        int col = ns * 16 + lr;
        if (col < 50) {
            float bias = b1[col];
#pragma unroll
            for (int r2 = 0; r2 < 4; ++r2) {
                int rowl = w * 16 + quad * 4 + r2;
                ttl[rowl * 52 + col] = fast_tanh(acc[ns][r2] + bias);
            }
        }
    }
    for (int idx = tid; idx < 600; idx += 256) A2l[idx] = A2[idx];
    if (tid < 12) b2l[tid] = b2[tid];
    __syncthreads();
    {
        const int row = tid & 63, rr = (tid >> 6) * 3;
        float a0 = b2l[rr], a1 = b2l[rr + 1], a2 = b2l[rr + 2];
        for (int jj = 0; jj < 50; ++jj) {
            float tv = ttl[row * 52 + jj];
            const float* ap = &A2l[jj * 12 + rr];
            a0 += tv * ap[0];
            a1 += tv * ap[1];
            a2 += tv * ap[2];
        }
        scl[row * 12 + rr]     = a0;
        scl[row * 12 + rr + 1] = a1;
        scl[row * 12 + rr + 2] = a2;
    }
    __syncthreads();
    if (tid < 64) {
        float v[12];
#pragma unroll
        for (int r = 0; r < 12; ++r) v[r] = scl[tid * 12 + r];
        float mx = v[0];
#pragma unroll
        for (int r = 1; r < 12; ++r) mx = fmaxf(mx, v[r]);
        float sm = 0.f;
#pragma unroll
        for (int r = 0; r < 12; ++r) { v[r] = __expf(v[r] - mx); sm += v[r]; }
        float inv = 1.f / sm;
#pragma unroll
        for (int r = 0; r < 12; ++r) v[r] *= inv;
        float* dst = att + (size_t)(m0 + tid) * 12;
        *(float4*)(dst)     = make_float4(v[0], v[1], v[2], v[3]);
        *(float4*)(dst + 4) = make_float4(v[4], v[5], v[6], v[7]);
        *(float4*)(dst + 8) = make_float4(v[8], v[9], v[10], v[11]);
    }
}

// ---------------------------------------------------------------------------
// Kernel D0: g = att^T att per batch, norms[b] = ||g - I||_F.
// ---------------------------------------------------------------------------
__global__ __launch_bounds__(256) void k_gatt(
        const float* __restrict__ att,
        float* __restrict__ norms)
{
    const int b = blockIdx.x;
    const int tid = threadIdx.x;
    __shared__ __align__(16) float al[9600];
    __shared__ float g_l[144];
    {
        const float4* src = (const float4*)(att + (size_t)b * 9600);
        float4* dst = (float4*)al;
        for (int e = tid; e < 2400; e += 256) dst[e] = src[e];
    }
    __syncthreads();
    if (tid < 144) {
        const int rr = tid / 12, ss = tid - rr * 12;
        float s2 = 0.f;
        for (int t = 0; t < 800; ++t)
            s2 += al[t * 12 + rr] * al[t * 12 + ss];
        g_l[tid] = s2;
    }
    __syncthreads();
    if (tid == 0) {
        float s2 = 0.f;
        for (int idx = 0; idx < 144; ++idx) {
            float v = g_l[idx] - ((idx / 12 == idx % 12) ? 1.f : 0.f);
            s2 += v * v;
        }
        norms[b] = sqrtf(s2);
    }
}

// ---------------------------------------------------------------------------
// Kernel D1 (v3): m[b][r][:] + squash -> v0g, THREE r per block.
// ---------------------------------------------------------------------------
__global__ __launch_bounds__(192) void k_poolm(
        const __hip_bfloat16* __restrict__ h,
        const float* __restrict__ att,
        float* __restrict__ v0g)      // [128][12][192] fp32
{
    const int b = blockIdx.x, r0 = blockIdx.y * 3;
    const int tid = threadIdx.x;
    __shared__ float al[3][800];
    __shared__ float red[3][3];
    __shared__ float sscl[3];

    for (int t = tid; t < 800; t += 192) {
        const float* ap = att + ((size_t)b * 800 + t) * 12 + r0;
        al[0][t] = ap[0];
        al[1][t] = ap[1];
        al[2][t] = ap[2];
    }
    __syncthreads();

    const unsigned short* hp = (const unsigned short*)h + (size_t)b * 800 * 192 + tid;
    float m0 = 0.f, m1 = 0.f, m2 = 0.f;
    for (int t0 = 0; t0 < 800; t0 += 8) {
#pragma unroll
        for (int q = 0; q < 8; ++q) {
            unsigned short hb = hp[(size_t)(t0 + q) * 192];
            float hv = __bfloat162float(*(const __hip_bfloat16*)&hb);
            m0 += hv * al[0][t0 + q];
            m1 += hv * al[1][t0 + q];
            m2 += hv * al[2][t0 + q];
        }
    }
    float s0 = m0 * m0, s1 = m1 * m1, s2 = m2 * m2;
#pragma unroll
    for (int off = 32; off; off >>= 1) {
        s0 += __shfl_down(s0, off);
        s1 += __shfl_down(s1, off);
        s2 += __shfl_down(s2, off);
    }
    if ((tid & 63) == 0) {
        red[0][tid >> 6] = s0; red[1][tid >> 6] = s1; red[2][tid >> 6] = s2;
    }
    __syncthreads();
    if (tid < 3) sscl[tid] = squash_scale(red[tid][0] + red[tid][1] + red[tid][2]);
    __syncthreads();
    float* vp = v0g + ((size_t)b * 12 + r0) * 192 + tid;
    vp[0]   = m0 * sscl[0];
    vp[192] = m1 * sscl[1];
    vp[384] = m2 * sscl[2];
}

// ---------------------------------------------------------------------------
// Kernel D2: u_hat GEMM per r: [128 x 192] @ [192 x 800]. Grid (12, 2, 13).
// ---------------------------------------------------------------------------
__global__ __launch_bounds__(256) void k_uhat(
        const float* __restrict__ v0g,
        const float* __restrict__ Wc,
        float* __restrict__ u_hat)    // [128][12][800] fp32
{
    const int r  = blockIdx.x;           // 0..11
    const int m0 = blockIdx.y * 64;      // 0,64
    const int n0 = blockIdx.z * 64;      // 0..768 (tail tile 32 valid)
    const int tid = threadIdx.x;
    __shared__ __align__(16) unsigned short At[64 * 200];
    __shared__ __align__(16) unsigned short Bt[64 * 200];
    for (int idx = tid; idx < 64 * 96; idx += 256) {
        int row = idx / 96, p = idx - row * 96;
        float2 f = *(const float2*)(v0g + ((size_t)(m0 + row) * 12 + r) * 192 + 2 * p);
        *(unsigned int*)(&At[row * 200 + 2 * p]) = pack_bf16x2(f.x, f.y);
    }
    for (int idx = tid; idx < 192 * 64; idx += 256) {
        int k = idx >> 6, nn = idx & 63;
        unsigned short v = 0;
        if (n0 + nn < 800) v = bf16_bits(Wc[((size_t)r * 192 + k) * 800 + n0 + nn]);
        Bt[nn * 200 + k] = v;
    }
    __syncthreads();
    const int w = tid >> 6, l = tid & 63;
    const int lr = l & 15, quad = l >> 4;
    f32x4 z4 = {0.f, 0.f, 0.f, 0.f};
    f32x4 acc[4];
#pragma unroll
    for (int i = 0; i < 4; ++i) acc[i] = z4;
#pragma unroll
    for (int kk = 0; kk < 6; ++kk) {
        bf16x8 af = *(const bf16x8*)(&At[(w * 16 + lr) * 200 + kk * 32 + quad * 8]);
#pragma unroll
        for (int ns = 0; ns < 4; ++ns) {
            bf16x8 bv = *(const bf16x8*)(&Bt[(ns * 16 + lr) * 200 + kk * 32 + quad * 8]);
            acc[ns] = __builtin_amdgcn_mfma_f32_16x16x32_bf16(af, bv, acc[ns], 0, 0, 0);
        }
    }
#pragma unroll
    for (int ns = 0; ns < 4; ++ns) {
        int cco = n0 + ns * 16 + lr;
        if (cco < 800) {
#pragma unroll
            for (int r2 = 0; r2 < 4; ++r2) {
                int brow = m0 + w * 16 + quad * 4 + r2;
                u_hat[((size_t)brow * 12 + r) * 800 + cco] = acc[ns][r2];
            }
        }
    }
}

// ---------------------------------------------------------------------------
// Kernel D3: dynamic routing per batch (u_hat in LDS), 3 iterations, write v.
// ---------------------------------------------------------------------------
__global__ __launch_bounds__(256) void k_route(
        const float* __restrict__ u_hat,
        float* __restrict__ out)
{
    const int b = blockIdx.x;
    const int tid = threadIdx.x;
    __shared__ __align__(16) float u_l[9600];
    __shared__ float blogl[600];
    __shared__ float c_l[600];
    __shared__ float s_l[800];
    __shared__ float v_l[800];
    __shared__ float scl[64];
    {
        const float4* src = (const float4*)(u_hat + (size_t)b * 9600);
        float4* dst = (float4*)u_l;
        for (int e = tid; e < 2400; e += 256) dst[e] = src[e];
    }
    for (int e = tid; e < 600; e += 256) blogl[e] = 0.f;
    __syncthreads();
    for (int it = 0; it < 3; ++it) {
        if (tid < 12) {
            float mx = -1e30f;
            for (int cc = 0; cc < 50; ++cc) mx = fmaxf(mx, blogl[tid * 50 + cc]);
            float sm = 0.f;
            for (int cc = 0; cc < 50; ++cc) {
                float e2 = __expf(blogl[tid * 50 + cc] - mx);
                c_l[tid * 50 + cc] = e2; sm += e2;
            }
            float inv = 1.f / sm;
            for (int cc = 0; cc < 50; ++cc) c_l[tid * 50 + cc] *= inv;
        }
        __syncthreads();
        for (int e = tid; e < 800; e += 256) {
            int cc = e >> 4;
            float sv = 0.f;
#pragma unroll
            for (int r = 0; r < 12; ++r) sv += c_l[r * 50 + cc] * u_l[r * 800 + e];
            s_l[e] = sv;
        }
        __syncthreads();
        for (int cc = tid; cc < 50; cc += 256) {
            float n2 = 0.f;
#pragma unroll
            for (int o = 0; o < 16; ++o) { float v = s_l[cc * 16 + o]; n2 += v * v; }
            scl[cc] = squash_scale(n2);
        }
        __syncthreads();
        for (int e = tid; e < 800; e += 256) v_l[e] = s_l[e] * scl[e >> 4];
        __syncthreads();
        if (it < 2) {
            for (int e = tid; e < 600; e += 256) {
                int cc = e % 50;
                float dd = 0.f;
#pragma unroll
                for (int o = 0; o < 16; ++o) dd += u_l[e * 16 + o] * v_l[cc * 16 + o];
                blogl[e] += dd;
            }
            __syncthreads();
        }
    }
    for (int e = tid; e < 800; e += 256) out[(size_t)b * 800 + e] = v_l[e];
}

// ---------------------------------------------------------------------------
// Kernel E: att_reg = mean(norms)
// ---------------------------------------------------------------------------
__global__ void k_reg(const float* __restrict__ norms, float* __restrict__ out)
{
    const int l = threadIdx.x;           // 64
    float v = norms[l] + norms[l + 64];
#pragma unroll
    for (int off = 32; off; off >>= 1) v += __shfl_down(v, off);
    if (l == 0) out[OUTV] = v * (1.f / 128.f);
}

// ---------------------------------------------------------------------------
extern "C" void kernel_launch(void* const* d_in, const int* in_sizes, int n_in,
                              void* d_out, int out_size, void* d_ws, size_t ws_size,
                              hipStream_t stream) {
    const int*   tokens = (const int*)d_in[0];
    const float* emb    = (const float*)d_in[1];
    const float* wih_f  = (const float*)d_in[2];
    const float* whh_f  = (const float*)d_in[3];
    const float* bih_f  = (const float*)d_in[4];
    const float* bhh_f  = (const float*)d_in[5];
    const float* wih_b  = (const float*)d_in[6];
    const float* whh_b  = (const float*)d_in[7];
    const float* bih_b  = (const float*)d_in[8];
    const float* bhh_b  = (const float*)d_in[9];
    const float* A1     = (const float*)d_in[10];
    const float* b1     = (const float*)d_in[11];
    const float* A2     = (const float*)d_in[12];
    const float* b2     = (const float*)d_in[13];
    const float* Wc     = (const float*)d_in[14];

    const size_t HB = 39321600;                  // hbuf: 102400*192*2 (bf16)
    const size_t XX = 26214400;                  // xx16: 102400*128*2 (f16)
    char* ws = (char*)d_ws;
    __hip_bfloat16* hbuf = (__hip_bfloat16*)ws;
    unsigned short* xx16 = (unsigned short*)(ws + HB);
    char* tail = ws + HB + XX;
    float*          att  = (float*)(tail);
    float*          nrm  = (float*)(tail + 4915200);
    float*          v0g  = (float*)(tail + 4915712);
    float*          uhat = (float*)(tail + 6095360);
    // Bpre aliases the uhat slot (dead until k_uhat, well after its readers).
    unsigned short* Bpre = (unsigned short*)(tail + 6095360);
    float* out = (float*)d_out;

    k_prep <<<390, 256, 0, stream>>>(wih_f, wih_b, A1, Bpre);
    k_embg <<<1600, 256, 0, stream>>>(tokens, emb, xx16);
    k_gru4f<<<dim3(200, 2), 384, 0, stream>>>(xx16, Bpre, bih_f, bih_b,
                                              whh_f, whh_b, bhh_f, bhh_b, hbuf, 0);
    k_attf <<<1600, 256, 0, stream>>>(hbuf, Bpre, b1, A2, b2, att);
    k_gatt <<<128, 256, 0, stream>>>(att, nrm);
    k_poolm<<<dim3(128, 4), 192, 0, stream>>>(hbuf, att, v0g);
    k_uhat <<<dim3(12, 2, 13), 256, 0, stream>>>(v0g, Wc, uhat);
    k_route<<<128, 256, 0, stream>>>(uhat, out);
    k_reg  <<<1, 64, 0, stream>>>(nrm, out);
}

// Round 11
// 369.904 us; speedup vs baseline: 1.3934x; 1.3934x over previous
//
#include <hip/hip_runtime.h>
#include <hip/hip_bf16.h>
#include <math.h>

typedef short bf16x8 __attribute__((ext_vector_type(8)));
typedef _Float16 half8 __attribute__((ext_vector_type(8)));
typedef float f32x4 __attribute__((ext_vector_type(4)));

#define B_   128
#define T_   800
#define E_   100
#define HC   192       // 2H
#define OUTV 102400    // B*C*O

__device__ inline float squash_scale(float n2) {
    return (n2 / (n2 + 1.f)) * rsqrtf(fmaxf(n2, 1e-30f));
}

__device__ inline unsigned short bf16_bits(float x) {
    __hip_bfloat16 h = __float2bfloat16(x);
    return *(unsigned short*)&h;
}

__device__ inline unsigned int pack_bf16x2(float a, float b) {
    return (unsigned int)bf16_bits(a) | ((unsigned int)bf16_bits(b) << 16);
}

__device__ inline void split_hilo(float x, unsigned short& hi, unsigned short& lo) {
    __hip_bfloat16 h = __float2bfloat16(x);
    float hf = __bfloat162float(h);
    hi = *(unsigned short*)&h;
    __hip_bfloat16 l = __float2bfloat16(x - hf);
    lo = *(unsigned short*)&l;
}

__device__ inline float f16u_to_f(unsigned short s) {
    _Float16 h;
    __builtin_memcpy(&h, &s, 2);
    return (float)h;
}

__device__ inline unsigned short f16_bits(float x) {
    _Float16 h = (_Float16)x;
    unsigned short b;
    __builtin_memcpy(&b, &h, 2);
    return b;
}

__device__ inline unsigned int pack_f16x2(float a, float b) {
    return (unsigned int)f16_bits(a) | ((unsigned int)f16_bits(b) << 16);
}

__device__ inline float fast_sigmoid(float x) { return 1.f / (1.f + __expf(-x)); }
__device__ inline float fast_tanh(float x) {
    float e = __expf(2.f * x);
    return 1.f - 2.f / (e + 1.f);
}

// LDS-only barrier: make LDS writes visible and sync the block WITHOUT
// draining vmcnt (global loads/stores stay in flight across the barrier).
__device__ inline void bar_lds_only() {
    asm volatile("s_waitcnt lgkmcnt(0)" ::: "memory");
    __builtin_amdgcn_s_barrier();
    asm volatile("" ::: "memory");
}

// 16-byte async global->LDS copy (per-lane addresses must be wave-linear in
// steps of 16 B on the LDS side — guaranteed by o = tid*8 (+ wave-uniform)).
__device__ inline void stage16(const unsigned short* g, unsigned short* l) {
#if __has_builtin(__builtin_amdgcn_global_load_lds)
    __builtin_amdgcn_global_load_lds(
        (const __attribute__((address_space(1))) unsigned int*)g,
        (__attribute__((address_space(3))) unsigned int*)l, 16, 0, 0);
#else
    *(uint4*)l = *(const uint4*)g;
#endif
}

// ---------------------------------------------------------------------------
// Kernel P (v2): pre-convert wih (both dirs) to the exact f16 tile image
// AND A1 (transposed) to hi/lo bf16 LDS tile images.
// ---------------------------------------------------------------------------
__global__ __launch_bounds__(256) void k_prep(
        const float* __restrict__ wih0, const float* __restrict__ wih1,
        const float* __restrict__ A1,
        unsigned short* __restrict__ Bpre)
{
    int idx = blockIdx.x * 256 + threadIdx.x;       // grid 390*256 == 99840
    if (idx >= 99840) return;
    if (idx < 87040) {
        int q = idx % 136;
        int r = idx / 136;                          // u*320 + gc
        int u2 = r / 320, gc = r % 320;
        const float* wih = u2 ? wih1 : wih0;
        unsigned short v = 0;
        if (q < 100 && gc < 288) v = f16_bits(wih[(size_t)gc * E_ + q]);
        Bpre[idx] = v;
    } else {
        int idx2 = idx - 87040;                     // [0, 12800)
        int nn = idx2 / 200, k = idx2 - nn * 200;
        unsigned short vh = 0, vl = 0;
        if (nn < 50 && k < 192) split_hilo(A1[k * 50 + nn], vh, vl);
        Bpre[87040 + idx2] = vh;
        Bpre[99840 + idx2] = vl;
    }
}

// ---------------------------------------------------------------------------
// Kernel A (v4, round-9 verified): gi for both directions, one block per
// 64-row m-tile.  gi3 "packet" layout consumed by k_gru4.
// ---------------------------------------------------------------------------
__global__ __launch_bounds__(256, 4) void k_gi2b(
        const int* __restrict__ tokens, const float* __restrict__ emb,
        const float* __restrict__ bih0, const float* __restrict__ bih1,
        const unsigned short* __restrict__ Bpre,
        unsigned short* __restrict__ g3_0, unsigned short* __restrict__ g3_1,
        int uoff, int ndir)
{
    const int m0 = blockIdx.x * 64;      // 1600 blocks
    const int tid = threadIdx.x;
    const int w = tid >> 6, l = tid & 63;
    const int lr = l & 15, quad = l >> 4;

    __shared__ __align__(16) unsigned short Bt[2][8704];   // 2 x 64 x 136 f16
    __shared__ float biasl[576];

    for (int i = tid; i < 576; i += 256)
        biasl[i] = (i < 288) ? bih0[i] : bih1[i - 288];

    // ---- A fragments: emb row for this lane's m-row, f16, K padded to 128
    const int trow = tokens[m0 + w * 16 + lr];
    const float* ap = emb + (size_t)trow * E_;
    half8 afr[4];
#pragma unroll
    for (int kk = 0; kk < 4; ++kk) {
        union { unsigned int u[4]; half8 h; } tmp;
#pragma unroll
        for (int pq = 0; pq < 4; ++pq) {
            int k0 = kk * 32 + quad * 8 + pq * 2;
            float2 f = {0.f, 0.f};
            if (k0 + 1 < E_) f = *(const float2*)(ap + k0);   // 8-B aligned
            tmp.u[pq] = pack_f16x2(f.x, f.y);
        }
        afr[kk] = tmp.h;
    }

    f32x4 z4 = {0.f, 0.f, 0.f, 0.f};
    f32x4 acc[18];
#pragma unroll
    for (int i = 0; i < 18; ++i) acc[i] = z4;

    const int group = w * 2 + (quad >> 1);
    const int lane_g = ((quad & 1) << 4) + lr;

    for (int u = uoff; u < uoff + ndir; ++u) {
        const unsigned short* bsrc = Bpre + (size_t)u * 43520;
        __syncthreads();                 // Bt free (prev dir / first use)
        for (int o = tid * 8; o < 8704; o += 2048)
            stage16(bsrc + o, &Bt[0][0] + o);
        __syncthreads();                 // tile 0 resident (+ biasl staged)
#pragma unroll
        for (int nt = 0; nt < 5; ++nt) {
            if (nt < 4) {                // prefetch next tile into other buf
                const unsigned short* s2 = bsrc + (size_t)(nt + 1) * 8704;
                unsigned short* d2 = &Bt[(nt + 1) & 1][0];
                for (int o = tid * 8; o < 8704; o += 2048)
                    stage16(s2 + o, d2 + o);
            }
            const unsigned short* bt = &Bt[nt & 1][0];
#pragma unroll
            for (int kk = 0; kk < 4; ++kk) {
#pragma unroll
                for (int ns = 0; ns < 4; ++ns) {
                    if (nt * 4 + ns < 18) {
                        half8 bv = *(const half8*)(bt + (ns * 16 + lr) * 136 + kk * 32 + quad * 8);
                        acc[nt * 4 + ns] =
                            __builtin_amdgcn_mfma_f32_16x16x32_f16(afr[kk], bv, acc[nt * 4 + ns], 0, 0, 0);
                    }
                }
            }
            if (nt < 4) __syncthreads(); // prefetch drained; bufs swap safely
        }
        // ---- epilogue: each lane owns 3 complete 48-B gi3 packets ----
        unsigned short* gi3 = u ? g3_1 : g3_0;
        const float* bl = biasl + u * 288;
        const size_t basep = ((size_t)(m0 >> 3) + group) * 2304 + (size_t)lane_g * 24;
#pragma unroll
        for (int wv3 = 0; wv3 < 3; ++wv3) {
            unsigned int uw[12];
#pragma unroll
            for (int pp = 0; pp < 2; ++pp)
#pragma unroll
                for (int gg = 0; gg < 3; ++gg) {
                    int nsg = gg * 6 + wv3 * 2 + pp;
                    float bias = bl[nsg * 16 + lr];
                    int s = pp * 3 + gg;
                    uw[2 * s]     = pack_f16x2(acc[nsg][0] + bias, acc[nsg][1] + bias);
                    uw[2 * s + 1] = pack_f16x2(acc[nsg][2] + bias, acc[nsg][3] + bias);
                }
            uint4* dst = (uint4*)(gi3 + basep + wv3 * 768);
            dst[0] = *(uint4*)&uw[0];
            dst[1] = *(uint4*)&uw[4];
            dst[2] = *(uint4*)&uw[8];
        }
        if (u + 1 < uoff + ndir) {
#pragma unroll
            for (int i = 0; i < 18; ++i) acc[i] = z4;
        }
    }
}

// ---------------------------------------------------------------------------
// Kernel B (round-4/9 verified @126us): MFMA GRU. Grid (200, ndir) x 384.
// ---------------------------------------------------------------------------
__global__ __launch_bounds__(384, 2) void k_gru4(
        const unsigned short* __restrict__ gi3_f,
        const unsigned short* __restrict__ gi3_b,
        const float* __restrict__ whh_f, const float* __restrict__ whh_b,
        const float* __restrict__ bhh_f, const float* __restrict__ bhh_b,
        __hip_bfloat16* __restrict__ hout, int uoff)
{
    const int tc = blockIdx.x;           // 0..199 (4 t-rows each)
    const int u  = blockIdx.y + uoff;    // 0 fwd, 1 bwd
    const int tid = threadIdx.x;
    const int wv2 = tid >> 6;            // col chunk cc = 0..5
    const int l   = tid & 63;
    const int c16 = l & 15, rg = l >> 4; // rg = local t-row (0..3) / k-sub
    const int gblk = tc >> 1, qd = tc & 1;
    const unsigned short* gi3 = u ? gi3_b : gi3_f;
    const float* whh = u ? whh_b : whh_f;
    const float* bhh = u ? bhh_b : bhh_f;

    __shared__ _Float16 h16[2][16 * 104];   // rows 4..15 stay zero (M pad)

    // ---- weights: 3 gates x 3 kchunks for col j = wv2*16 + c16 ----
    const int j = wv2 * 16 + c16;
    half8 bw[3][3];
    float bias[3];
#pragma unroll
    for (int g = 0; g < 3; ++g) {
        int n = g * 96 + j;
        bias[g] = bhh[n];
#pragma unroll
        for (int kc = 0; kc < 3; ++kc) {
            const float* wp = whh + (size_t)n * 96 + kc * 32 + rg * 8;
            float4 f0 = *(const float4*)wp;
            float4 f1 = *(const float4*)(wp + 4);
            half8 hb;
            hb[0] = (_Float16)f0.x; hb[1] = (_Float16)f0.y;
            hb[2] = (_Float16)f0.z; hb[3] = (_Float16)f0.w;
            hb[4] = (_Float16)f1.x; hb[5] = (_Float16)f1.y;
            hb[6] = (_Float16)f1.z; hb[7] = (_Float16)f1.w;
            bw[g][kc] = hb;
        }
    }

    for (int idx = tid; idx < 2 * 16 * 104; idx += 384)
        (&h16[0][0])[idx] = (_Float16)0.f;
    float hst = 0.f;
    __syncthreads();

    // ---- gi3 addressing (dwords). packet = (i*100+gblk)*1152 dwords;
    // within: wv3*384 + lane_g*12 + 6*pp + (rg>>1); gates at stride 2.
    const int wv3 = wv2 >> 1, pp = wv2 & 1;
    const unsigned int* gbase = (const unsigned int*)gi3;
    const int i0 = u ? 127 : 0;
    long long pdw = (long long)(i0 * 100 + gblk) * 1152
                  + wv3 * 384 + (qd * 16 + c16) * 12 + 6 * pp + (rg >> 1);
    const long long dstep = (u ? -1LL : 1LL) * 115200;   // 100*1152 dwords

    unsigned int cur0 = gbase[pdw], cur1 = gbase[pdw + 2], cur2 = gbase[pdw + 4];

    // ---- hout running pointer ----
    const int t = tc * 4 + rg;
    __hip_bfloat16* hptr = hout + ((size_t)i0 * T_ + t) * HC + u * 96 + j;
    const long long hstep = (u ? -1LL : 1LL) * (T_ * HC);

    const int sh = (rg & 1) * 16;
    int cb = 0;

    for (int s = 0; s < 128; ++s) {
        // issue next step's gi3 loads FIRST (consumed next step -> a full
        // step of latency cover; never drained by the LDS-only barrier)
        unsigned int nx0 = cur0, nx1 = cur1, nx2 = cur2;
        if (s < 127) {
            pdw += dstep;
            nx0 = gbase[pdw]; nx1 = gbase[pdw + 2]; nx2 = gbase[pdw + 4];
        }

        const _Float16* hb = &h16[cb][0];
        half8 a0 = *(const half8*)(&hb[c16 * 104 + 0  + rg * 8]);
        half8 a1 = *(const half8*)(&hb[c16 * 104 + 32 + rg * 8]);
        half8 a2 = *(const half8*)(&hb[c16 * 104 + 64 + rg * 8]);

        f32x4 acc[3];
#pragma unroll
        for (int g = 0; g < 3; ++g) {
            f32x4 c = {0.f, 0.f, 0.f, 0.f};
            c = __builtin_amdgcn_mfma_f32_16x16x32_f16(a0, bw[g][0], c, 0, 0, 0);
            c = __builtin_amdgcn_mfma_f32_16x16x32_f16(a1, bw[g][1], c, 0, 0, 0);
            c = __builtin_amdgcn_mfma_f32_16x16x32_f16(a2, bw[g][2], c, 0, 0, 0);
            acc[g] = c;
        }

        // route C[rg][c16] -> this lane: pull all 4 regs from lane c16,
        // then select by the READER's rg. (wave-local; no barrier needed)
        float rt[3];
#pragma unroll
        for (int g = 0; g < 3; ++g) {
            float v0 = __shfl(acc[g][0], c16);
            float v1 = __shfl(acc[g][1], c16);
            float v2 = __shfl(acc[g][2], c16);
            float v3 = __shfl(acc[g][3], c16);
            float lo = (rg & 1) ? v1 : v0;
            float hi = (rg & 1) ? v3 : v2;
            rt[g] = (rg & 2) ? hi : lo;
        }

        float gr = f16u_to_f((unsigned short)(cur0 >> sh));
        float gz = f16u_to_f((unsigned short)(cur1 >> sh));
        float gn = f16u_to_f((unsigned short)(cur2 >> sh));
        float r  = fast_sigmoid(gr + rt[0] + bias[0]);
        float z  = fast_sigmoid(gz + rt[1] + bias[1]);
        float nn = fast_tanh(gn + r * (rt[2] + bias[2]));
        float hp = (1.f - z) * nn + z * hst;
        hst = hp;

        h16[cb ^ 1][rg * 104 + j] = (_Float16)hp;   // write OTHER buffer
        *hptr = __float2bfloat16(hp);

        bar_lds_only();                  // lgkmcnt(0) + s_barrier, no vmcnt

        cur0 = nx0; cur1 = nx1; cur2 = nx2;
        hptr += hstep;
        cb ^= 1;
    }
}

// ---------------------------------------------------------------------------
// Kernel C (fused att1+att2, round-9 verified): att = softmax(tanh(h@A1+b1)@A2
// + b2, axis=-1).
// ---------------------------------------------------------------------------
__global__ __launch_bounds__(256) void k_attf(
        const __hip_bfloat16* __restrict__ h,
        const unsigned short* __restrict__ Bpre,   // A1 tiles at +87040
        const float* __restrict__ b1,
        const float* __restrict__ A2,
        const float* __restrict__ b2,
        float* __restrict__ att)
{
    const int m0 = blockIdx.x * 64;      // 1600 blocks
    const int tid = threadIdx.x;
    __shared__ __align__(16) unsigned char poolA[64 * 200 * 2];  // At | phase2
    __shared__ __align__(16) unsigned short Bhi[64 * 200];
    __shared__ __align__(16) unsigned short Blo[64 * 200];
    unsigned short* At = (unsigned short*)poolA;
    float* ttl = (float*)poolA;                   // [64][52]  13312 B
    float* A2l = (float*)(poolA + 13312);         // 600 f32    2400 B
    float* b2l = (float*)(poolA + 15712);         // 12 f32       48 B
    float* scl = (float*)(poolA + 15760);         // [64][12]   3072 B

    for (int idx = tid; idx < 64 * 96; idx += 256) {
        int r = idx / 96, p = idx - r * 96;
        unsigned int v = *(const unsigned int*)((const unsigned short*)h + ((size_t)(m0 + r) * HC + 2 * p));
        *(unsigned int*)(&At[r * 200 + 2 * p]) = v;
    }
    {
        const unsigned short* hsrc = Bpre + 87040;
        const unsigned short* lsrc = Bpre + 99840;
        for (int o = tid * 8; o < 12800; o += 2048) {
            stage16(hsrc + o, &Bhi[0] + o);
            stage16(lsrc + o, &Blo[0] + o);
        }
    }
    __syncthreads();
    const int w = tid >> 6, l = tid & 63;
    const int lr = l & 15, quad = l >> 4;
    f32x4 z4 = {0.f, 0.f, 0.f, 0.f};
    f32x4 acc[4];
#pragma unroll
    for (int i = 0; i < 4; ++i) acc[i] = z4;
#pragma unroll
    for (int kk = 0; kk < 6; ++kk) {
        bf16x8 af = *(const bf16x8*)(&At[(w * 16 + lr) * 200 + kk * 32 + quad * 8]);
#pragma unroll
        for (int ns = 0; ns < 4; ++ns) {
            bf16x8 bh = *(const bf16x8*)(&Bhi[(ns * 16 + lr) * 200 + kk * 32 + quad * 8]);
            bf16x8 bl = *(const bf16x8*)(&Blo[(ns * 16 + lr) * 200 + kk * 32 + quad * 8]);
            acc[ns] = __builtin_amdgcn_mfma_f32_16x16x32_bf16(af, bh, acc[ns], 0, 0, 0);
            acc[ns] = __builtin_amdgcn_mfma_f32_16x16x32_bf16(af, bl, acc[ns], 0, 0, 0);
        }
    }
    __syncthreads();                     // At dead -> ttl overlay safe
#pragma unroll
    for (int ns = 0; ns < 4; ++ns) {
        int col = ns * 16 + lr;
        if (col < 50) {
            float bias = b1[col];
#pragma unroll
            for (int r2 = 0; r2 < 4; ++r2) {
                int rowl = w * 16 + quad * 4 + r2;
                ttl[rowl * 52 + col] = fast_tanh(acc[ns][r2] + bias);
            }
        }
    }
    for (int idx = tid; idx < 600; idx += 256) A2l[idx] = A2[idx];
    if (tid < 12) b2l[tid] = b2[tid];
    __syncthreads();
    {
        const int row = tid & 63, rr = (tid >> 6) * 3;
        float a0 = b2l[rr], a1 = b2l[rr + 1], a2 = b2l[rr + 2];
        for (int jj = 0; jj < 50; ++jj) {
            float tv = ttl[row * 52 + jj];
            const float* ap = &A2l[jj * 12 + rr];
            a0 += tv * ap[0];
            a1 += tv * ap[1];
            a2 += tv * ap[2];
        }
        scl[row * 12 + rr]     = a0;
        scl[row * 12 + rr + 1] = a1;
        scl[row * 12 + rr + 2] = a2;
    }
    __syncthreads();
    if (tid < 64) {
        float v[12];
#pragma unroll
        for (int r = 0; r < 12; ++r) v[r] = scl[tid * 12 + r];
        float mx = v[0];
#pragma unroll
        for (int r = 1; r < 12; ++r) mx = fmaxf(mx, v[r]);
        float sm = 0.f;
#pragma unroll
        for (int r = 0; r < 12; ++r) { v[r] = __expf(v[r] - mx); sm += v[r]; }
        float inv = 1.f / sm;
#pragma unroll
        for (int r = 0; r < 12; ++r) v[r] *= inv;
        float* dst = att + (size_t)(m0 + tid) * 12;
        *(float4*)(dst)     = make_float4(v[0], v[1], v[2], v[3]);
        *(float4*)(dst + 4) = make_float4(v[4], v[5], v[6], v[7]);
        *(float4*)(dst + 8) = make_float4(v[8], v[9], v[10], v[11]);
    }
}

// ---------------------------------------------------------------------------
// Kernel D01 (round-11, fuses gatt+poolm on the matrix pipe): per batch b,
//   m = att^T h  (M=12 pad 16, N=192, K=800)  and  g = att^T att (N=12),
// then squash -> v0g and norms[b] = ||g - I||_F.
// att split hi/lo bf16 (k_att1's verified precision pattern; lo*lo dropped,
// ~2e-5).  h staged LINEARLY via global_load_lds (rows of b are contiguous);
// B-fragments read column-wise from the [t][192] tile (contiguous per lane).
// g's B-fragment == m's A-fragment registers (attT is [r][t] = [n][k]).
// Replaces ~55us of DS-broadcast dot products with ~18 MFMAs/wave/tile.
// ---------------------------------------------------------------------------
__global__ __launch_bounds__(256) void k_pgat(
        const __hip_bfloat16* __restrict__ h,
        const float* __restrict__ att,
        float* __restrict__ v0g,      // [128][12][192] fp32
        float* __restrict__ norms)
{
    const int b = blockIdx.x;
    const int tid = threadIdx.x;
    const int w = tid >> 6, l = tid & 63;
    const int lr = l & 15, quad = l >> 4;

    __shared__ __align__(16) unsigned short Bt[64 * 192];   // h tile, bf16
    __shared__ __align__(16) unsigned short aTh[16 * 72];   // attT hi (bf16)
    __shared__ __align__(16) unsigned short aTl[16 * 72];   // attT lo
    __shared__ float redm[4][16];
    __shared__ float sclb[12];

    // zero attT once (rows 12..15 and pad cols stay zero forever)
    for (int e = tid; e < 16 * 72; e += 256) { aTh[e] = 0; aTl[e] = 0; }

    f32x4 z4 = {0.f, 0.f, 0.f, 0.f};
    f32x4 accm[3];
#pragma unroll
    for (int i = 0; i < 3; ++i) accm[i] = z4;
    f32x4 gac = z4;

    const unsigned short* hsrc0 = (const unsigned short*)h + (size_t)b * 800 * 192;

    for (int t0 = 0; t0 < 800; t0 += 64) {
        const int nvalid = (800 - t0 < 64) ? (800 - t0) : 64;   // 64 or 32
        __syncthreads();                 // prev tile's reads done
        if (nvalid < 64) {               // zero-pad tail rows (NaN guard)
            for (int o = tid * 8; o < (64 - nvalid) * 192; o += 2048)
                *(uint4*)(&Bt[nvalid * 192 + o]) = make_uint4(0, 0, 0, 0);
        }
        for (int o = tid * 8; o < nvalid * 192; o += 2048)
            stage16(hsrc0 + (size_t)t0 * 192 + o, &Bt[0] + o);
        // attT: transpose + hi/lo split (t >= valid -> 0)
        for (int e = tid; e < 768; e += 256) {
            int t = e / 12, r = e - (e / 12) * 12;
            float av = (t < nvalid) ? att[((size_t)b * 800 + t0 + t) * 12 + r] : 0.f;
            unsigned short vh, vl;
            split_hilo(av, vh, vl);
            aTh[r * 72 + t] = vh;
            aTl[r * 72 + t] = vl;
        }
        __syncthreads();                 // stage16 drained + attT visible

#pragma unroll
        for (int kk = 0; kk < 2; ++kk) {
            bf16x8 ah = *(const bf16x8*)(&aTh[lr * 72 + kk * 32 + quad * 8]);
            bf16x8 al = *(const bf16x8*)(&aTl[lr * 72 + kk * 32 + quad * 8]);
#pragma unroll
            for (int ni = 0; ni < 3; ++ni) {
                const int n0 = (w * 3 + ni) * 16;
                bf16x8 bh;
#pragma unroll
                for (int i = 0; i < 8; ++i)
                    bh[i] = (short)Bt[(kk * 32 + quad * 8 + i) * 192 + n0 + lr];
                accm[ni] = __builtin_amdgcn_mfma_f32_16x16x32_bf16(ah, bh, accm[ni], 0, 0, 0);
                accm[ni] = __builtin_amdgcn_mfma_f32_16x16x32_bf16(al, bh, accm[ni], 0, 0, 0);
            }
            // g: B-fragment == A-fragment registers (attT is [n][k] too)
            gac = __builtin_amdgcn_mfma_f32_16x16x32_bf16(ah, ah, gac, 0, 0, 0);
            gac = __builtin_amdgcn_mfma_f32_16x16x32_bf16(ah, al, gac, 0, 0, 0);
            gac = __builtin_amdgcn_mfma_f32_16x16x32_bf16(al, ah, gac, 0, 0, 0);
        }
    }

    // ---- squash: n2[row] = sum over cols of m^2 ----
    float p[4];
#pragma unroll
    for (int r2 = 0; r2 < 4; ++r2) {
        float s = 0.f;
#pragma unroll
        for (int ni = 0; ni < 3; ++ni) { float v = accm[ni][r2]; s += v * v; }
#pragma unroll
        for (int m = 1; m < 16; m <<= 1) s += __shfl_xor(s, m);
        p[r2] = s;
    }
    if (lr == 0) {
#pragma unroll
        for (int r2 = 0; r2 < 4; ++r2) redm[w][quad * 4 + r2] = p[r2];
    }
    __syncthreads();
    if (tid < 12)
        sclb[tid] = squash_scale(redm[0][tid] + redm[1][tid] + redm[2][tid] + redm[3][tid]);
    __syncthreads();

    // ---- v0g write: lane owns (row = quad*4+r2, col = (w*3+ni)*16+lr) ----
    if (quad < 3) {
#pragma unroll
        for (int ni = 0; ni < 3; ++ni) {
#pragma unroll
            for (int r2 = 0; r2 < 4; ++r2) {
                int row = quad * 4 + r2;
                int col = (w * 3 + ni) * 16 + lr;
                v0g[((size_t)b * 12 + row) * 192 + col] = accm[ni][r2] * sclb[row];
            }
        }
    }

    // ---- norms from wave 0's g ----
    if (w == 0) {
        float s = 0.f;
#pragma unroll
        for (int r2 = 0; r2 < 4; ++r2) {
            int rr = quad * 4 + r2;
            if (rr < 12 && lr < 12) {
                float d = gac[r2] - ((rr == lr) ? 1.f : 0.f);
                s += d * d;
            }
        }
#pragma unroll
        for (int m = 1; m < 64; m <<= 1) s += __shfl_xor(s, m);
        if (l == 0) norms[b] = sqrtf(s);
    }
}

// ---------------------------------------------------------------------------
// Kernel D2: u_hat GEMM per r: [128 x 192] @ [192 x 800]. Grid (12, 2, 13).
// ---------------------------------------------------------------------------
__global__ __launch_bounds__(256) void k_uhat(
        const float* __restrict__ v0g,
        const float* __restrict__ Wc,
        float* __restrict__ u_hat)    // [128][12][800] fp32
{
    const int r  = blockIdx.x;           // 0..11
    const int m0 = blockIdx.y * 64;      // 0,64
    const int n0 = blockIdx.z * 64;      // 0..768 (tail tile 32 valid)
    const int tid = threadIdx.x;
    __shared__ __align__(16) unsigned short At[64 * 200];
    __shared__ __align__(16) unsigned short Bt[64 * 200];
    for (int idx = tid; idx < 64 * 96; idx += 256) {
        int row = idx / 96, p = idx - row * 96;
        float2 f = *(const float2*)(v0g + ((size_t)(m0 + row) * 12 + r) * 192 + 2 * p);
        *(unsigned int*)(&At[row * 200 + 2 * p]) = pack_bf16x2(f.x, f.y);
    }
    for (int idx = tid; idx < 192 * 64; idx += 256) {
        int k = idx >> 6, nn = idx & 63;
        unsigned short v = 0;
        if (n0 + nn < 800) v = bf16_bits(Wc[((size_t)r * 192 + k) * 800 + n0 + nn]);
        Bt[nn * 200 + k] = v;
    }
    __syncthreads();
    const int w = tid >> 6, l = tid & 63;
    const int lr = l & 15, quad = l >> 4;
    f32x4 z4 = {0.f, 0.f, 0.f, 0.f};
    f32x4 acc[4];
#pragma unroll
    for (int i = 0; i < 4; ++i) acc[i] = z4;
#pragma unroll
    for (int kk = 0; kk < 6; ++kk) {
        bf16x8 af = *(const bf16x8*)(&At[(w * 16 + lr) * 200 + kk * 32 + quad * 8]);
#pragma unroll
        for (int ns = 0; ns < 4; ++ns) {
            bf16x8 bv = *(const bf16x8*)(&Bt[(ns * 16 + lr) * 200 + kk * 32 + quad * 8]);
            acc[ns] = __builtin_amdgcn_mfma_f32_16x16x32_bf16(af, bv, acc[ns], 0, 0, 0);
        }
    }
#pragma unroll
    for (int ns = 0; ns < 4; ++ns) {
        int cco = n0 + ns * 16 + lr;
        if (cco < 800) {
#pragma unroll
            for (int r2 = 0; r2 < 4; ++r2) {
                int brow = m0 + w * 16 + quad * 4 + r2;
                u_hat[((size_t)brow * 12 + r) * 800 + cco] = acc[ns][r2];
            }
        }
    }
}

// ---------------------------------------------------------------------------
// Kernel D3: dynamic routing per batch (u_hat in LDS), 3 iterations, write v.
// ---------------------------------------------------------------------------
__global__ __launch_bounds__(256) void k_route(
        const float* __restrict__ u_hat,
        float* __restrict__ out)
{
    const int b = blockIdx.x;
    const int tid = threadIdx.x;
    __shared__ __align__(16) float u_l[9600];
    __shared__ float blogl[600];
    __shared__ float c_l[600];
    __shared__ float s_l[800];
    __shared__ float v_l[800];
    __shared__ float scl[64];
    {
        const float4* src = (const float4*)(u_hat + (size_t)b * 9600);
        float4* dst = (float4*)u_l;
        for (int e = tid; e < 2400; e += 256) dst[e] = src[e];
    }
    for (int e = tid; e < 600; e += 256) blogl[e] = 0.f;
    __syncthreads();
    for (int it = 0; it < 3; ++it) {
        if (tid < 12) {
            float mx = -1e30f;
            for (int cc = 0; cc < 50; ++cc) mx = fmaxf(mx, blogl[tid * 50 + cc]);
            float sm = 0.f;
            for (int cc = 0; cc < 50; ++cc) {
                float e2 = __expf(blogl[tid * 50 + cc] - mx);
                c_l[tid * 50 + cc] = e2; sm += e2;
            }
            float inv = 1.f / sm;
            for (int cc = 0; cc < 50; ++cc) c_l[tid * 50 + cc] *= inv;
        }
        __syncthreads();
        for (int e = tid; e < 800; e += 256) {
            int cc = e >> 4;
            float sv = 0.f;
#pragma unroll
            for (int r = 0; r < 12; ++r) sv += c_l[r * 50 + cc] * u_l[r * 800 + e];
            s_l[e] = sv;
        }
        __syncthreads();
        for (int cc = tid; cc < 50; cc += 256) {
            float n2 = 0.f;
#pragma unroll
            for (int o = 0; o < 16; ++o) { float v = s_l[cc * 16 + o]; n2 += v * v; }
            scl[cc] = squash_scale(n2);
        }
        __syncthreads();
        for (int e = tid; e < 800; e += 256) v_l[e] = s_l[e] * scl[e >> 4];
        __syncthreads();
        if (it < 2) {
            for (int e = tid; e < 600; e += 256) {
                int cc = e % 50;
                float dd = 0.f;
#pragma unroll
                for (int o = 0; o < 16; ++o) dd += u_l[e * 16 + o] * v_l[cc * 16 + o];
                blogl[e] += dd;
            }
            __syncthreads();
        }
    }
    for (int e = tid; e < 800; e += 256) out[(size_t)b * 800 + e] = v_l[e];
}

// ---------------------------------------------------------------------------
// Kernel E: att_reg = mean(norms)
// ---------------------------------------------------------------------------
__global__ void k_reg(const float* __restrict__ norms, float* __restrict__ out)
{
    const int l = threadIdx.x;           // 64
    float v = norms[l] + norms[l + 64];
#pragma unroll
    for (int off = 32; off; off >>= 1) v += __shfl_down(v, off);
    if (l == 0) out[OUTV] = v * (1.f / 128.f);
}

// ---------------------------------------------------------------------------
extern "C" void kernel_launch(void* const* d_in, const int* in_sizes, int n_in,
                              void* d_out, int out_size, void* d_ws, size_t ws_size,
                              hipStream_t stream) {
    const int*   tokens = (const int*)d_in[0];
    const float* emb    = (const float*)d_in[1];
    const float* wih_f  = (const float*)d_in[2];
    const float* whh_f  = (const float*)d_in[3];
    const float* bih_f  = (const float*)d_in[4];
    const float* bhh_f  = (const float*)d_in[5];
    const float* wih_b  = (const float*)d_in[6];
    const float* whh_b  = (const float*)d_in[7];
    const float* bih_b  = (const float*)d_in[8];
    const float* bhh_b  = (const float*)d_in[9];
    const float* A1     = (const float*)d_in[10];
    const float* b1     = (const float*)d_in[11];
    const float* A2     = (const float*)d_in[12];
    const float* b2     = (const float*)d_in[13];
    const float* Wc     = (const float*)d_in[14];

    const size_t HB = 39321600;                  // hbuf: 102400*192*2 (bf16)
    const size_t GI = 58982400;                  // gi3 one dir: 128*100*2304*2
    const size_t TAIL = 11010560;
    char* ws = (char*)d_ws;
    __hip_bfloat16* hbuf = (__hip_bfloat16*)ws;
    float* out = (float*)d_out;

    if (ws_size >= HB + 2 * GI + TAIL) {
        // ---- primary: both directions resident, single merged GRU ----
        unsigned short* gi_f = (unsigned short*)(ws + HB);
        unsigned short* gi_b = (unsigned short*)(ws + HB + GI);
        char* tail = ws + HB + 2 * GI;
        float*          att  = (float*)(tail);
        float*          nrm  = (float*)(tail + 4915200);
        float*          v0g  = (float*)(tail + 4915712);
        float*          uhat = (float*)(tail + 6095360);
        // Bpre aliases the uhat slot (dead until k_uhat, well after k_attf).
        unsigned short* Bpre = (unsigned short*)(tail + 6095360);
        k_prep <<<390, 256, 0, stream>>>(wih_f, wih_b, A1, Bpre);
        k_gi2b <<<1600, 256, 0, stream>>>(tokens, emb, bih_f, bih_b, Bpre, gi_f, gi_b, 0, 2);
        k_gru4<<<dim3(200, 2), 384, 0, stream>>>(gi_f, gi_b, whh_f, whh_b, bhh_f, bhh_b, hbuf, 0);
        k_attf <<<1600, 256, 0, stream>>>(hbuf, Bpre, b1, A2, b2, att);
        k_pgat <<<128, 256, 0, stream>>>(hbuf, att, v0g, nrm);
        k_uhat <<<dim3(12, 2, 13), 256, 0, stream>>>(v0g, Wc, uhat);
        k_route<<<128, 256, 0, stream>>>(uhat, out);
        k_reg  <<<1, 64, 0, stream>>>(nrm, out);
    } else {
        // ---- compact: one gi3 buffer, directions sequential ----
        unsigned short* gi1 = (unsigned short*)(ws + HB);
        char* tail = ws + HB + GI;
        float*          att  = (float*)(tail);
        float*          nrm  = (float*)(tail + 4915200);
        float*          v0g  = (float*)(tail + 4915712);
        float*          uhat = (float*)(tail + 6095360);
        unsigned short* Bpre = (unsigned short*)(tail + 6095360);
        k_prep <<<390, 256, 0, stream>>>(wih_f, wih_b, A1, Bpre);
        k_gi2b <<<1600, 256, 0, stream>>>(tokens, emb, bih_f, bih_b, Bpre, gi1, gi1, 0, 1);
        k_gru4<<<dim3(200, 1), 384, 0, stream>>>(gi1, gi1, whh_f, whh_b, bhh_f, bhh_b, hbuf, 0);
        k_gi2b <<<1600, 256, 0, stream>>>(tokens, emb, bih_f, bih_b, Bpre, gi1, gi1, 1, 1);
        k_gru4<<<dim3(200, 1), 384, 0, stream>>>(gi1, gi1, whh_f, whh_b, bhh_f, bhh_b, hbuf, 1);
        k_attf <<<1600, 256, 0, stream>>>(hbuf, Bpre, b1, A2, b2, att);
        k_pgat <<<128, 256, 0, stream>>>(hbuf, att, v0g, nrm);
        k_uhat <<<dim3(12, 2, 13), 256, 0, stream>>>(v0g, Wc, uhat);
        k_route<<<128, 256, 0, stream>>>(uhat, out);
        k_reg  <<<1, 64, 0, stream>>>(nrm, out);
    }
}